// Round 7
// baseline (165.354 us; speedup 1.0000x reference)
//
#include <hip/hip_runtime.h>
#include <math.h>

// ---------------- workspace layout (bytes) ----------------
// [0)            double sum
// [16)           unsigned minkey[64]
// [16+256)       unsigned maxkey[64]
// [16+512)       float u7[7]   (separable 1-D gaussian weights)

__device__ __forceinline__ unsigned fkey(float f) {
    unsigned u = __float_as_uint(f);
    return (u & 0x80000000u) ? ~u : (u | 0x80000000u);
}
__device__ __forceinline__ float funkey(unsigned k) {
    return __uint_as_float((k & 0x80000000u) ? (k & 0x7FFFFFFFu) : ~k);
}

__global__ void init_ws(const float* __restrict__ w, float* __restrict__ u7,
                        unsigned* __restrict__ mink, unsigned* __restrict__ maxk,
                        double* __restrict__ sum) {
    int t = threadIdx.x;
    if (t == 0) *sum = 0.0;
    if (t < 64) { mink[t] = 0xFFFFFFFFu; maxk[t] = 0u; }
    if (t < 7) {
        float s = 0.f;
        for (int j = 0; j < 7; ++j) s += w[t * 7 + j];
        u7[t] = s;  // row sums of normalized 2-D window == 1-D weights
    }
}

// per-batch min/max of Y. 16 blocks per batch, 256 threads, float4 loads.
__global__ __launch_bounds__(256) void minmax_kernel(const float4* __restrict__ Y,
                                                     unsigned* __restrict__ mink,
                                                     unsigned* __restrict__ maxk) {
    int b = blockIdx.x >> 4, ch = blockIdx.x & 15;
    const float4* p = Y + (size_t)b * 65536 + (size_t)ch * 4096 + threadIdx.x;
    float lmin = INFINITY, lmax = -INFINITY;
#pragma unroll
    for (int i = 0; i < 16; ++i) {
        float4 v = p[(size_t)i * 256];
        lmin = fminf(lmin, fminf(fminf(v.x, v.y), fminf(v.z, v.w)));
        lmax = fmaxf(lmax, fmaxf(fmaxf(v.x, v.y), fmaxf(v.z, v.w)));
    }
#pragma unroll
    for (int off = 32; off; off >>= 1) {
        lmin = fminf(lmin, __shfl_down(lmin, off));
        lmax = fmaxf(lmax, __shfl_down(lmax, off));
    }
    if ((threadIdx.x & 63) == 0) {
        atomicMin(&mink[b], fkey(lmin));
        atomicMax(&maxk[b], fkey(lmax));
    }
}

// ---------------------------------------------------------------------------
// Main SSIM kernel. EXACT r4 geometry (proven 67us / WRITE=64B): tile 256 cols
// x 32 rows, 1 col/thread, grid = 64 img * 2 colstrips * 16 rowstrips = 2048.
// Delta vs r4 (single change under test): 4-channel formulation {x,y,q=x^2+y^2,
// xy} staged as float4 -> hblur is 7 ds_read_b128 + 28 fma (was 14 b64 + 49),
// ring 28 regs (was 35), emit 12 ops (was 16). Same mod-7/mod-2 macro-literal
// schedule (no runtime-indexed arrays -> no scratch).
// ---------------------------------------------------------------------------
__global__ __launch_bounds__(256, 4) void ssim_kernel(const float* __restrict__ X,
                                                      const float* __restrict__ Yg,
                                                      const float* __restrict__ u7,
                                                      const unsigned* __restrict__ mink,
                                                      const unsigned* __restrict__ maxk,
                                                      double* __restrict__ sum) {
    __shared__ float4 s4[2][262];      // L = col - c0 + 3, L in [0,261]
    __shared__ float warpsum[4];

    const int blk = blockIdx.x;
    const int b   = blk >> 5;          // image
    const int sub = blk & 31;
    const int cs  = sub & 1;           // col strip
    const int rs  = sub >> 1;          // row strip (0..15)
    const int c0  = cs << 8;
    const int r0  = rs << 5;
    const int t   = threadIdx.x;

    float u[7];
#pragma unroll
    for (int i = 0; i < 7; ++i) u[i] = u7[i];

    const float dr = funkey(maxk[b]) - funkey(mink[b]);
    float C1 = 0.01f * dr; C1 *= C1;
    float C2 = 0.03f * dr; C2 *= C2;
    const float cn  = 49.f / 48.f;
    const float cn2 = 2.f * cn;

    const float* __restrict__ Xb = X  + ((size_t)b << 18);
    const float* __restrict__ Yb = Yg + ((size_t)b << 18);

    const int  c    = c0 + t;                     // main col, always in-image
    const bool hasE = (t < 6);                    // halo: L 0..2, 259..261
    const int  eL   = (t < 3) ? t : (t + 256);
    const int  ecol = c0 + eL - 3;
    const bool eok  = (ecol >= 0) && (ecol < 512);
    const int  ec   = min(max(ecol, 0), 511);

    float fx[2], fy[2], ex[2], ey[2];             // prefetch regs (row parity)
    float phx[7], phy[7], phq[7], phxy[7];        // mod-7 ring, 4 channels
    float ssacc = 0.f;

#define LOADROW(P, JJ) do {                                                   \
    int r_ = r0 - 3 + (JJ);                                                   \
    if (r_ >= 0 && r_ < 512) {   /* block-uniform branch */                   \
        const float* xp_ = Xb + ((size_t)r_ << 9);                            \
        const float* yp_ = Yb + ((size_t)r_ << 9);                            \
        fx[(P)] = xp_[c]; fy[(P)] = yp_[c];                                   \
        if (hasE) { ex[(P)] = eok ? xp_[ec] : 0.f;                            \
                    ey[(P)] = eok ? yp_[ec] : 0.f; }                          \
    } else {                                                                  \
        fx[(P)] = 0.f; fy[(P)] = 0.f; ex[(P)] = 0.f; ey[(P)] = 0.f;           \
    }                                                                         \
} while (0)

#define WRITEROW(P) do {                                                      \
    float q_  = fmaf(fx[(P)], fx[(P)], fy[(P)] * fy[(P)]);                    \
    float xy_ = fx[(P)] * fy[(P)];                                            \
    s4[(P)][t + 3] = make_float4(fx[(P)], fy[(P)], q_, xy_);                  \
    if (hasE) {                                                               \
        float qe_  = fmaf(ex[(P)], ex[(P)], ey[(P)] * ey[(P)]);               \
        float xye_ = ex[(P)] * ey[(P)];                                       \
        s4[(P)][eL] = make_float4(ex[(P)], ey[(P)], qe_, xye_);               \
    }                                                                         \
} while (0)

#define HBLUR(BUF, SLOT) do {                                                 \
    float hx_ = 0.f, hy_ = 0.f, hq_ = 0.f, hxy_ = 0.f;                        \
    _Pragma("unroll")                                                         \
    for (int k_ = 0; k_ < 7; ++k_) {                                          \
        float4 v_ = s4[(BUF)][t + k_];                                        \
        hx_  = fmaf(u[k_], v_.x, hx_);                                        \
        hy_  = fmaf(u[k_], v_.y, hy_);                                        \
        hq_  = fmaf(u[k_], v_.z, hq_);                                        \
        hxy_ = fmaf(u[k_], v_.w, hxy_);                                       \
    }                                                                         \
    phx[(SLOT)] = hx_; phy[(SLOT)] = hy_;                                     \
    phq[(SLOT)] = hq_; phxy[(SLOT)] = hxy_;                                   \
} while (0)

// vertical blur: tap k reads slot (J+1+k)%7 with weight u[k]
#define VS(a, J) fmaf(u[6], a[(J) % 7], fmaf(u[5], a[((J)+6) % 7],            \
               fmaf(u[4], a[((J)+5) % 7], fmaf(u[3], a[((J)+4) % 7],          \
               fmaf(u[2], a[((J)+3) % 7], fmaf(u[1], a[((J)+2) % 7],          \
               u[0] * a[((J)+1) % 7]))))))

#define EMIT(J) do {                                                          \
    float mux = VS(phx, (J)), muy = VS(phy, (J));                             \
    float mq  = VS(phq, (J)), mxy = VS(phxy, (J));                            \
    float mux2 = mux * mux, muy2 = muy * muy, muxy = mux * muy;               \
    float m2 = mux2 + muy2;                                                   \
    float A_ = fmaf(muxy, 2.f, C1);          /* 2 muxy + C1        */         \
    float B_ = fmaf(mxy - muxy, cn2, C2);    /* 2 sxy + C2         */         \
    float D_ = m2 + C1;                                                       \
    float E_ = fmaf(mq - m2, cn, C2);        /* sxx + syy + C2     */         \
    ssacc = fmaf(A_ * B_, __builtin_amdgcn_rcpf(D_ * E_), ssacc);             \
} while (0)

#define PSTEP(J) do {                                                         \
    HBLUR((J) & 1, (J) % 7);                                                  \
    WRITEROW(((J) + 1) & 1);                                                  \
    LOADROW(((J) + 1) & 1, (J) + 3);                                          \
    __syncthreads();                                                          \
} while (0)

#define MSTEP(J) do {                                                         \
    HBLUR((J) & 1, (J) % 7);                                                  \
    EMIT(J);                                                                  \
    WRITEROW(((J) + 1) & 1);                                                  \
    LOADROW(((J) + 1) & 1, jb + (J) + 3);                                     \
    __syncthreads();                                                          \
} while (0)

#define MSTEP_NL(J) do {                                                      \
    HBLUR((J) & 1, (J) % 7);                                                  \
    EMIT(J);                                                                  \
    WRITEROW(((J) + 1) & 1);                                                  \
    __syncthreads();                                                          \
} while (0)

#define MSTEP_END(J) do {                                                     \
    HBLUR((J) & 1, (J) % 7);                                                  \
    EMIT(J);                                                                  \
} while (0)

    // pre-prologue: rows 0,1 loaded; row 0 staged to buf0; row 2 in flight
    LOADROW(0, 0);
    LOADROW(1, 1);
    WRITEROW(0);
    LOADROW(0, 2);
    __syncthreads();

    // prologue: rows 0..5 fill ring slots 0..5 (loads rows 3..8)
    PSTEP(0); PSTEP(1); PSTEP(2); PSTEP(3); PSTEP(4); PSTEP(5);

    // main: rows 6..33 (outputs 0..27); loads rows 9..36
    for (int g = 0; g < 2; ++g) {
        const int jb = 14 * g;
        MSTEP(6);  MSTEP(7);  MSTEP(8);  MSTEP(9);  MSTEP(10); MSTEP(11); MSTEP(12);
        MSTEP(13); MSTEP(14); MSTEP(15); MSTEP(16); MSTEP(17); MSTEP(18); MSTEP(19);
    }

    // tail: rows 34..37 (outputs 28..31)
    {
        const int jb = 28;
        MSTEP(6);        // row 34, loads row 37
        MSTEP_NL(7);     // row 35
        MSTEP_NL(8);     // row 36, stages row 37
        MSTEP_END(9);    // row 37
    }

#undef LOADROW
#undef WRITEROW
#undef HBLUR
#undef VS
#undef EMIT
#undef PSTEP
#undef MSTEP
#undef MSTEP_NL
#undef MSTEP_END

    // block reduction: wave shuffle -> LDS -> one double atomic per block
#pragma unroll
    for (int off = 32; off; off >>= 1) ssacc += __shfl_down(ssacc, off);
    if ((t & 63) == 0) warpsum[t >> 6] = ssacc;
    __syncthreads();
    if (t == 0) {
        double sm = (double)warpsum[0] + (double)warpsum[1] +
                    (double)warpsum[2] + (double)warpsum[3];
        atomicAdd(sum, sm);
    }
}

__global__ void finalize_kernel(const double* __restrict__ sum, float* __restrict__ out) {
    out[0] = (float)(1.0 - (*sum) / (64.0 * 512.0 * 512.0));
}

extern "C" void kernel_launch(void* const* d_in, const int* in_sizes, int n_in,
                              void* d_out, int out_size, void* d_ws, size_t ws_size,
                              hipStream_t stream) {
    const float* X = (const float*)d_in[0];
    const float* Y = (const float*)d_in[1];
    const float* W = (const float*)d_in[2];

    char* ws = (char*)d_ws;
    double* sum = (double*)(ws + 0);
    unsigned* mink = (unsigned*)(ws + 16);
    unsigned* maxk = (unsigned*)(ws + 16 + 256);
    float* u7 = (float*)(ws + 16 + 512);

    init_ws<<<1, 64, 0, stream>>>(W, u7, mink, maxk, sum);
    minmax_kernel<<<1024, 256, 0, stream>>>((const float4*)Y, mink, maxk);
    ssim_kernel<<<2048, 256, 0, stream>>>(X, Y, u7, mink, maxk, sum);
    finalize_kernel<<<1, 1, 0, stream>>>(sum, (float*)d_out);
}

// Round 8
// 132.567 us; speedup vs baseline: 1.2473x; 1.2473x over previous
//
#include <hip/hip_runtime.h>
#include <math.h>

// ---------------- workspace layout (bytes) ----------------
// [0)            double sum
// [16)           unsigned minkey[64]
// [16+256)       unsigned maxkey[64]
// [16+512)       float u7[7]   (separable 1-D gaussian weights)

__device__ __forceinline__ unsigned fkey(float f) {
    unsigned u = __float_as_uint(f);
    return (u & 0x80000000u) ? ~u : (u | 0x80000000u);
}
__device__ __forceinline__ float funkey(unsigned k) {
    return __uint_as_float((k & 0x80000000u) ? (k & 0x7FFFFFFFu) : ~k);
}

__global__ void init_ws(const float* __restrict__ w, float* __restrict__ u7,
                        unsigned* __restrict__ mink, unsigned* __restrict__ maxk,
                        double* __restrict__ sum) {
    int t = threadIdx.x;
    if (t == 0) *sum = 0.0;
    if (t < 64) { mink[t] = 0xFFFFFFFFu; maxk[t] = 0u; }
    if (t < 7) {
        float s = 0.f;
        for (int j = 0; j < 7; ++j) s += w[t * 7 + j];
        u7[t] = s;  // row sums of normalized 2-D window == 1-D weights
    }
}

// per-batch min/max of Y. 16 blocks per batch, 256 threads, float4 loads.
__global__ __launch_bounds__(256) void minmax_kernel(const float4* __restrict__ Y,
                                                     unsigned* __restrict__ mink,
                                                     unsigned* __restrict__ maxk) {
    int b = blockIdx.x >> 4, ch = blockIdx.x & 15;
    const float4* p = Y + (size_t)b * 65536 + (size_t)ch * 4096 + threadIdx.x;
    float lmin = INFINITY, lmax = -INFINITY;
#pragma unroll
    for (int i = 0; i < 16; ++i) {
        float4 v = p[(size_t)i * 256];
        lmin = fminf(lmin, fminf(fminf(v.x, v.y), fminf(v.z, v.w)));
        lmax = fmaxf(lmax, fmaxf(fmaxf(v.x, v.y), fmaxf(v.z, v.w)));
    }
#pragma unroll
    for (int off = 32; off; off >>= 1) {
        lmin = fminf(lmin, __shfl_down(lmin, off));
        lmax = fmaxf(lmax, __shfl_down(lmax, off));
    }
    if ((threadIdx.x & 63) == 0) {
        atomicMin(&mink[b], fkey(lmin));
        atomicMax(&maxk[b], fkey(lmax));
    }
}

// ---------------------------------------------------------------------------
// Main SSIM kernel. EXACT r4 geometry (proven 67us / WRITE=64B): tile 256 cols
// x 32 rows, 1 col/thread, grid = 64 img * 2 colstrips * 16 rowstrips = 2048.
// 4-channel math {x, y, q=x^2+y^2, xy} staged as TWO float2 LDS buffers
// (r4's exact proven b64 access pattern; r6/r7 showed float4 staging provokes
// a per-step scratch spill). amdgpu_waves_per_eu(4,4): min=4 caps VGPR at 128,
// max=4 removes the allocator's incentive to spill its way under the 64-reg
// occupancy tier (the r6/r7 failure mechanism).
// Same mod-7/mod-2 macro-literal schedule (no runtime-indexed arrays).
// ---------------------------------------------------------------------------
__global__ __attribute__((amdgpu_waves_per_eu(4, 4))) __launch_bounds__(256)
void ssim_kernel(const float* __restrict__ X,
                 const float* __restrict__ Yg,
                 const float* __restrict__ u7,
                 const unsigned* __restrict__ mink,
                 const unsigned* __restrict__ maxk,
                 double* __restrict__ sum) {
    __shared__ float2 sxy[2][262];     // {x, y},  L = col - c0 + 3
    __shared__ float2 sqp[2][262];     // {q, xy}
    __shared__ float warpsum[4];

    const int blk = blockIdx.x;
    const int b   = blk >> 5;          // image
    const int sub = blk & 31;
    const int cs  = sub & 1;           // col strip
    const int rs  = sub >> 1;          // row strip (0..15)
    const int c0  = cs << 8;
    const int r0  = rs << 5;
    const int t   = threadIdx.x;

    float u[7];
#pragma unroll
    for (int i = 0; i < 7; ++i) u[i] = u7[i];

    const float dr = funkey(maxk[b]) - funkey(mink[b]);
    float C1 = 0.01f * dr; C1 *= C1;
    float C2 = 0.03f * dr; C2 *= C2;
    const float cn  = 49.f / 48.f;
    const float cn2 = 2.f * cn;

    const float* __restrict__ Xb = X  + ((size_t)b << 18);
    const float* __restrict__ Yb = Yg + ((size_t)b << 18);

    const int  c    = c0 + t;                     // main col, always in-image
    const bool hasE = (t < 6);                    // halo: L 0..2, 259..261
    const int  eL   = (t < 3) ? t : (t + 256);
    const int  ecol = c0 + eL - 3;
    const bool eok  = (ecol >= 0) && (ecol < 512);
    const int  ec   = min(max(ecol, 0), 511);

    float fx[2], fy[2], ex[2], ey[2];             // prefetch regs (row parity)
    float phx[7], phy[7], phq[7], phxy[7];        // mod-7 ring, 4 channels
    float ssacc = 0.f;

#define LOADROW(P, JJ) do {                                                   \
    int r_ = r0 - 3 + (JJ);                                                   \
    if (r_ >= 0 && r_ < 512) {   /* block-uniform branch */                   \
        const float* xp_ = Xb + ((size_t)r_ << 9);                            \
        const float* yp_ = Yb + ((size_t)r_ << 9);                            \
        fx[(P)] = xp_[c]; fy[(P)] = yp_[c];                                   \
        if (hasE) { ex[(P)] = eok ? xp_[ec] : 0.f;                            \
                    ey[(P)] = eok ? yp_[ec] : 0.f; }                          \
    } else {                                                                  \
        fx[(P)] = 0.f; fy[(P)] = 0.f; ex[(P)] = 0.f; ey[(P)] = 0.f;           \
    }                                                                         \
} while (0)

#define WRITEROW(P) do {                                                      \
    float q_  = fmaf(fx[(P)], fx[(P)], fy[(P)] * fy[(P)]);                    \
    float xy_ = fx[(P)] * fy[(P)];                                            \
    sxy[(P)][t + 3] = make_float2(fx[(P)], fy[(P)]);                          \
    sqp[(P)][t + 3] = make_float2(q_, xy_);                                   \
    if (hasE) {                                                               \
        float qe_  = fmaf(ex[(P)], ex[(P)], ey[(P)] * ey[(P)]);               \
        float xye_ = ex[(P)] * ey[(P)];                                       \
        sxy[(P)][eL] = make_float2(ex[(P)], ey[(P)]);                         \
        sqp[(P)][eL] = make_float2(qe_, xye_);                                \
    }                                                                         \
} while (0)

#define HBLUR(BUF, SLOT) do {                                                 \
    float hx_ = 0.f, hy_ = 0.f, hq_ = 0.f, hxy_ = 0.f;                        \
    _Pragma("unroll")                                                         \
    for (int k_ = 0; k_ < 7; ++k_) {                                          \
        float2 a_ = sxy[(BUF)][t + k_];                                       \
        float2 b_ = sqp[(BUF)][t + k_];                                       \
        hx_  = fmaf(u[k_], a_.x, hx_);                                        \
        hy_  = fmaf(u[k_], a_.y, hy_);                                        \
        hq_  = fmaf(u[k_], b_.x, hq_);                                        \
        hxy_ = fmaf(u[k_], b_.y, hxy_);                                       \
    }                                                                         \
    phx[(SLOT)] = hx_; phy[(SLOT)] = hy_;                                     \
    phq[(SLOT)] = hq_; phxy[(SLOT)] = hxy_;                                   \
} while (0)

// vertical blur: tap k reads slot (J+1+k)%7 with weight u[k]
#define VS(a, J) fmaf(u[6], a[(J) % 7], fmaf(u[5], a[((J)+6) % 7],            \
               fmaf(u[4], a[((J)+5) % 7], fmaf(u[3], a[((J)+4) % 7],          \
               fmaf(u[2], a[((J)+3) % 7], fmaf(u[1], a[((J)+2) % 7],          \
               u[0] * a[((J)+1) % 7]))))))

#define EMIT(J) do {                                                          \
    float mux = VS(phx, (J)), muy = VS(phy, (J));                             \
    float mq  = VS(phq, (J)), mxy = VS(phxy, (J));                            \
    float mux2 = mux * mux, muy2 = muy * muy, muxy = mux * muy;               \
    float m2 = mux2 + muy2;                                                   \
    float A_ = fmaf(muxy, 2.f, C1);          /* 2 muxy + C1        */         \
    float B_ = fmaf(mxy - muxy, cn2, C2);    /* 2 sxy + C2         */         \
    float D_ = m2 + C1;                                                       \
    float E_ = fmaf(mq - m2, cn, C2);        /* sxx + syy + C2     */         \
    ssacc = fmaf(A_ * B_, __builtin_amdgcn_rcpf(D_ * E_), ssacc);             \
} while (0)

#define PSTEP(J) do {                                                         \
    HBLUR((J) & 1, (J) % 7);                                                  \
    WRITEROW(((J) + 1) & 1);                                                  \
    LOADROW(((J) + 1) & 1, (J) + 3);                                          \
    __syncthreads();                                                          \
} while (0)

#define MSTEP(J) do {                                                         \
    HBLUR((J) & 1, (J) % 7);                                                  \
    EMIT(J);                                                                  \
    WRITEROW(((J) + 1) & 1);                                                  \
    LOADROW(((J) + 1) & 1, jb + (J) + 3);                                     \
    __syncthreads();                                                          \
} while (0)

#define MSTEP_NL(J) do {                                                      \
    HBLUR((J) & 1, (J) % 7);                                                  \
    EMIT(J);                                                                  \
    WRITEROW(((J) + 1) & 1);                                                  \
    __syncthreads();                                                          \
} while (0)

#define MSTEP_END(J) do {                                                     \
    HBLUR((J) & 1, (J) % 7);                                                  \
    EMIT(J);                                                                  \
} while (0)

    // pre-prologue: rows 0,1 loaded; row 0 staged to buf0; row 2 in flight
    LOADROW(0, 0);
    LOADROW(1, 1);
    WRITEROW(0);
    LOADROW(0, 2);
    __syncthreads();

    // prologue: rows 0..5 fill ring slots 0..5 (loads rows 3..8)
    PSTEP(0); PSTEP(1); PSTEP(2); PSTEP(3); PSTEP(4); PSTEP(5);

    // main: rows 6..33 (outputs 0..27); loads rows 9..36
    for (int g = 0; g < 2; ++g) {
        const int jb = 14 * g;
        MSTEP(6);  MSTEP(7);  MSTEP(8);  MSTEP(9);  MSTEP(10); MSTEP(11); MSTEP(12);
        MSTEP(13); MSTEP(14); MSTEP(15); MSTEP(16); MSTEP(17); MSTEP(18); MSTEP(19);
    }

    // tail: rows 34..37 (outputs 28..31)
    {
        const int jb = 28;
        MSTEP(6);        // row 34, loads row 37
        MSTEP_NL(7);     // row 35
        MSTEP_NL(8);     // row 36, stages row 37
        MSTEP_END(9);    // row 37
    }

#undef LOADROW
#undef WRITEROW
#undef HBLUR
#undef VS
#undef EMIT
#undef PSTEP
#undef MSTEP
#undef MSTEP_NL
#undef MSTEP_END

    // block reduction: wave shuffle -> LDS -> one double atomic per block
#pragma unroll
    for (int off = 32; off; off >>= 1) ssacc += __shfl_down(ssacc, off);
    if ((t & 63) == 0) warpsum[t >> 6] = ssacc;
    __syncthreads();
    if (t == 0) {
        double sm = (double)warpsum[0] + (double)warpsum[1] +
                    (double)warpsum[2] + (double)warpsum[3];
        atomicAdd(sum, sm);
    }
}

__global__ void finalize_kernel(const double* __restrict__ sum, float* __restrict__ out) {
    out[0] = (float)(1.0 - (*sum) / (64.0 * 512.0 * 512.0));
}

extern "C" void kernel_launch(void* const* d_in, const int* in_sizes, int n_in,
                              void* d_out, int out_size, void* d_ws, size_t ws_size,
                              hipStream_t stream) {
    const float* X = (const float*)d_in[0];
    const float* Y = (const float*)d_in[1];
    const float* W = (const float*)d_in[2];

    char* ws = (char*)d_ws;
    double* sum = (double*)(ws + 0);
    unsigned* mink = (unsigned*)(ws + 16);
    unsigned* maxk = (unsigned*)(ws + 16 + 256);
    float* u7 = (float*)(ws + 16 + 512);

    init_ws<<<1, 64, 0, stream>>>(W, u7, mink, maxk, sum);
    minmax_kernel<<<1024, 256, 0, stream>>>((const float4*)Y, mink, maxk);
    ssim_kernel<<<2048, 256, 0, stream>>>(X, Y, u7, mink, maxk, sum);
    finalize_kernel<<<1, 1, 0, stream>>>(sum, (float*)d_out);
}

// Round 9
// 107.884 us; speedup vs baseline: 1.5327x; 1.2288x over previous
//
#include <hip/hip_runtime.h>
#include <math.h>

// ---------------- workspace layout (bytes) ----------------
// [0)            double sum
// [16)           unsigned minkey[64]
// [16+256)       unsigned maxkey[64]
// [16+512)       float u7[7]   (separable 1-D gaussian weights)

__device__ __forceinline__ unsigned fkey(float f) {
    unsigned u = __float_as_uint(f);
    return (u & 0x80000000u) ? ~u : (u | 0x80000000u);
}
__device__ __forceinline__ float funkey(unsigned k) {
    return __uint_as_float((k & 0x80000000u) ? (k & 0x7FFFFFFFu) : ~k);
}

__global__ void init_ws(const float* __restrict__ w, float* __restrict__ u7,
                        unsigned* __restrict__ mink, unsigned* __restrict__ maxk,
                        double* __restrict__ sum) {
    int t = threadIdx.x;
    if (t == 0) *sum = 0.0;
    if (t < 64) { mink[t] = 0xFFFFFFFFu; maxk[t] = 0u; }
    if (t < 7) {
        float s = 0.f;
        for (int j = 0; j < 7; ++j) s += w[t * 7 + j];
        u7[t] = s;  // row sums of normalized 2-D window == 1-D weights
    }
}

// per-batch min/max of Y. 16 blocks per batch, 256 threads, float4 loads.
__global__ __launch_bounds__(256) void minmax_kernel(const float4* __restrict__ Y,
                                                     unsigned* __restrict__ mink,
                                                     unsigned* __restrict__ maxk) {
    int b = blockIdx.x >> 4, ch = blockIdx.x & 15;
    const float4* p = Y + (size_t)b * 65536 + (size_t)ch * 4096 + threadIdx.x;
    float lmin = INFINITY, lmax = -INFINITY;
#pragma unroll
    for (int i = 0; i < 16; ++i) {
        float4 v = p[(size_t)i * 256];
        lmin = fminf(lmin, fminf(fminf(v.x, v.y), fminf(v.z, v.w)));
        lmax = fmaxf(lmax, fmaxf(fmaxf(v.x, v.y), fmaxf(v.z, v.w)));
    }
#pragma unroll
    for (int off = 32; off; off >>= 1) {
        lmin = fminf(lmin, __shfl_down(lmin, off));
        lmax = fmaxf(lmax, __shfl_down(lmax, off));
    }
    if ((threadIdx.x & 63) == 0) {
        atomicMin(&mink[b], fkey(lmin));
        atomicMax(&maxk[b], fkey(lmax));
    }
}

// ---------------------------------------------------------------------------
// Main SSIM kernel. EXACT r4 per-step body and math (proven 60 VGPR, no
// scratch, 67.8us): 5-channel {x,y,xx,yy,xy}, {x,y} float2 LDS staging,
// mod-7 macro-literal ring. Deltas vs r4 (zero added liveness per step):
//  * 4 LDS row buffers (mod-4) instead of 2, barrier only after ODD rows:
//    38 -> 20 barriers/block. Window {even J, J+1} reads bufs {J,J+1}%4,
//    writes bufs {J+2,J+3}%4 - disjoint, race-free.
//  * prefetch regs split A(even rows)/B(odd rows): loads issued 2 rows
//    (~400 VALU ops) before consumption, same 8 scalar regs as r4.
//  * period lcm(4,7)=28 == main span -> fully unrolled literal schedule.
// Tile: 256 cols x 32 rows, grid = 64 img * 2 cs * 16 rs = 2048 blocks.
// ---------------------------------------------------------------------------
__global__ __launch_bounds__(256, 4) void ssim_kernel(const float* __restrict__ X,
                                                      const float* __restrict__ Yg,
                                                      const float* __restrict__ u7,
                                                      const unsigned* __restrict__ mink,
                                                      const unsigned* __restrict__ maxk,
                                                      double* __restrict__ sum) {
    __shared__ float2 s[4][264];       // L = col - c0 + 3, L in [0,261]
    __shared__ float warpsum[4];

    const int blk = blockIdx.x;
    const int b   = blk >> 5;          // image
    const int sub = blk & 31;
    const int cs  = sub & 1;           // col strip
    const int rs  = sub >> 1;          // row strip (0..15)
    const int c0  = cs << 8;
    const int r0  = rs << 5;
    const int t   = threadIdx.x;

    float u[7];
#pragma unroll
    for (int i = 0; i < 7; ++i) u[i] = u7[i];

    const float dr = funkey(maxk[b]) - funkey(mink[b]);
    float C1 = 0.01f * dr; C1 *= C1;
    float C2 = 0.03f * dr; C2 *= C2;
    const float cn = 49.f / 48.f;

    const float* __restrict__ Xb = X  + ((size_t)b << 18);
    const float* __restrict__ Yb = Yg + ((size_t)b << 18);

    const int  c    = c0 + t;                     // main col, always in-image
    const bool hasE = (t < 6);                    // halo: L 0..2, 259..261
    const int  eL   = (t < 3) ? t : (t + 256);
    const int  ecol = c0 + eL - 3;
    const bool eok  = (ecol >= 0) && (ecol < 512);
    const int  ec   = min(max(ecol, 0), 511);

    // prefetch regs: A = even rows, B = odd rows (each lives exactly 2 steps)
    float fxa, fya, exa, eya, fxb, fyb, exb, eyb;
    float phx[7], phy[7], phxx[7], phyy[7], phxy[7];   // mod-7 ring
    float ssacc = 0.f;

#define LOADA(JJ) do {                                                        \
    int r_ = r0 - 3 + (JJ);                                                   \
    if (r_ >= 0 && r_ < 512) {   /* block-uniform branch */                   \
        const float* xp_ = Xb + ((size_t)r_ << 9);                            \
        const float* yp_ = Yb + ((size_t)r_ << 9);                            \
        fxa = xp_[c]; fya = yp_[c];                                           \
        if (hasE) { exa = eok ? xp_[ec] : 0.f; eya = eok ? yp_[ec] : 0.f; }   \
    } else { fxa = 0.f; fya = 0.f; exa = 0.f; eya = 0.f; }                    \
} while (0)

#define LOADB(JJ) do {                                                        \
    int r_ = r0 - 3 + (JJ);                                                   \
    if (r_ >= 0 && r_ < 512) {                                                \
        const float* xp_ = Xb + ((size_t)r_ << 9);                            \
        const float* yp_ = Yb + ((size_t)r_ << 9);                            \
        fxb = xp_[c]; fyb = yp_[c];                                           \
        if (hasE) { exb = eok ? xp_[ec] : 0.f; eyb = eok ? yp_[ec] : 0.f; }   \
    } else { fxb = 0.f; fyb = 0.f; exb = 0.f; eyb = 0.f; }                    \
} while (0)

#define WRITEA(BUF) do {                                                      \
    s[(BUF)][t + 3] = make_float2(fxa, fya);                                  \
    if (hasE) s[(BUF)][eL] = make_float2(exa, eya);                           \
} while (0)

#define WRITEB(BUF) do {                                                      \
    s[(BUF)][t + 3] = make_float2(fxb, fyb);                                  \
    if (hasE) s[(BUF)][eL] = make_float2(exb, eyb);                           \
} while (0)

#define HBLUR(BUF, SLOT) do {                                                 \
    float hx_ = 0.f, hy_ = 0.f, hxx_ = 0.f, hyy_ = 0.f, hxy_ = 0.f;           \
    _Pragma("unroll")                                                         \
    for (int k_ = 0; k_ < 7; ++k_) {                                          \
        float2 v_ = s[(BUF)][t + k_];                                         \
        float wx_ = u[k_] * v_.x, wy_ = u[k_] * v_.y;                         \
        hx_ += wx_; hy_ += wy_;                                               \
        hxx_ = fmaf(wx_, v_.x, hxx_);                                         \
        hxy_ = fmaf(wx_, v_.y, hxy_);                                         \
        hyy_ = fmaf(wy_, v_.y, hyy_);                                         \
    }                                                                         \
    phx[(SLOT)] = hx_; phy[(SLOT)] = hy_;                                     \
    phxx[(SLOT)] = hxx_; phyy[(SLOT)] = hyy_; phxy[(SLOT)] = hxy_;            \
} while (0)

// vertical blur: tap k reads slot (J+1+k)%7 with weight u[k]
#define VS(a, J) fmaf(u[6], a[(J) % 7], fmaf(u[5], a[((J)+6) % 7],            \
               fmaf(u[4], a[((J)+5) % 7], fmaf(u[3], a[((J)+4) % 7],          \
               fmaf(u[2], a[((J)+3) % 7], fmaf(u[1], a[((J)+2) % 7],          \
               u[0] * a[((J)+1) % 7]))))))

#define EMIT(J) do {                                                          \
    float mux = VS(phx, (J)), muy = VS(phy, (J));                             \
    float mxx = VS(phxx, (J)), myy = VS(phyy, (J)), mxy = VS(phxy, (J));      \
    float mux2 = mux * mux, muy2 = muy * muy, muxy = mux * muy;               \
    float sxx = (mxx - mux2) * cn;                                            \
    float syy = (myy - muy2) * cn;                                            \
    float sxy = (mxy - muxy) * cn;                                            \
    float num = (2.f * muxy + C1) * (2.f * sxy + C2);                         \
    float den = (mux2 + muy2 + C1) * (sxx + syy + C2);                        \
    ssacc = fmaf(num, __builtin_amdgcn_rcpf(den), ssacc);                     \
} while (0)

// even-row step: no barrier. odd-row step: barrier.
#define PSTEPA(J) do { HBLUR((J)%4, (J)%7); WRITEA(((J)+2)%4); LOADA((J)+4); } while (0)
#define PSTEPB(J) do { HBLUR((J)%4, (J)%7); WRITEB(((J)+2)%4); LOADB((J)+4); \
                       __syncthreads(); } while (0)
#define MSTEPA(J) do { HBLUR((J)%4, (J)%7); EMIT(J); WRITEA(((J)+2)%4); LOADA((J)+4); } while (0)
#define MSTEPB(J) do { HBLUR((J)%4, (J)%7); EMIT(J); WRITEB(((J)+2)%4); LOADB((J)+4); \
                       __syncthreads(); } while (0)
#define MSTEPA_NL(J) do { HBLUR((J)%4, (J)%7); EMIT(J); WRITEA(((J)+2)%4); } while (0)
#define MSTEPB_NL(J) do { HBLUR((J)%4, (J)%7); EMIT(J); WRITEB(((J)+2)%4); \
                          __syncthreads(); } while (0)
#define MEND(J)   do { HBLUR((J)%4, (J)%7); EMIT(J); } while (0)

    // pre-prologue: rows 0,1 -> bufs 0,1; rows 2,3 in flight
    LOADA(0); LOADB(1);
    WRITEA(0); WRITEB(1);
    LOADA(2); LOADB(3);
    __syncthreads();

    // prologue: rows 0..5 fill ring slots 0..5 (no outputs)
    PSTEPA(0); PSTEPB(1);     // writes rows 2,3 -> bufs 2,3; loads 4,5
    PSTEPA(2); PSTEPB(3);     // writes rows 4,5 -> bufs 0,1; loads 6,7
    PSTEPA(4); PSTEPB(5);     // writes rows 6,7 -> bufs 2,3; loads 8,9

    // main: rows 6..33 (outputs 0..27), fully unrolled (period 28 = lcm(4,7))
    MSTEPA(6);  MSTEPB(7);
    MSTEPA(8);  MSTEPB(9);
    MSTEPA(10); MSTEPB(11);
    MSTEPA(12); MSTEPB(13);
    MSTEPA(14); MSTEPB(15);
    MSTEPA(16); MSTEPB(17);
    MSTEPA(18); MSTEPB(19);
    MSTEPA(20); MSTEPB(21);
    MSTEPA(22); MSTEPB(23);
    MSTEPA(24); MSTEPB(25);
    MSTEPA(26); MSTEPB(27);
    MSTEPA(28); MSTEPB(29);
    MSTEPA(30); MSTEPB(31);
    MSTEPA(32); MSTEPB(33);   // writes rows 34,35; loads rows 36,37

    // tail: rows 34..37 (outputs 28..31)
    MSTEPA_NL(34);            // reads buf2; writes row36 -> buf0
    MSTEPB_NL(35);            // reads buf3; writes row37 -> buf1; barrier
    MEND(36);                 // reads buf0
    MEND(37);                 // reads buf1

#undef LOADA
#undef LOADB
#undef WRITEA
#undef WRITEB
#undef HBLUR
#undef VS
#undef EMIT
#undef PSTEPA
#undef PSTEPB
#undef MSTEPA
#undef MSTEPB
#undef MSTEPA_NL
#undef MSTEPB_NL
#undef MEND

    // block reduction: wave shuffle -> LDS -> one double atomic per block
#pragma unroll
    for (int off = 32; off; off >>= 1) ssacc += __shfl_down(ssacc, off);
    if ((t & 63) == 0) warpsum[t >> 6] = ssacc;
    __syncthreads();
    if (t == 0) {
        double sm = (double)warpsum[0] + (double)warpsum[1] +
                    (double)warpsum[2] + (double)warpsum[3];
        atomicAdd(sum, sm);
    }
}

__global__ void finalize_kernel(const double* __restrict__ sum, float* __restrict__ out) {
    out[0] = (float)(1.0 - (*sum) / (64.0 * 512.0 * 512.0));
}

extern "C" void kernel_launch(void* const* d_in, const int* in_sizes, int n_in,
                              void* d_out, int out_size, void* d_ws, size_t ws_size,
                              hipStream_t stream) {
    const float* X = (const float*)d_in[0];
    const float* Y = (const float*)d_in[1];
    const float* W = (const float*)d_in[2];

    char* ws = (char*)d_ws;
    double* sum = (double*)(ws + 0);
    unsigned* mink = (unsigned*)(ws + 16);
    unsigned* maxk = (unsigned*)(ws + 16 + 256);
    float* u7 = (float*)(ws + 16 + 512);

    init_ws<<<1, 64, 0, stream>>>(W, u7, mink, maxk, sum);
    minmax_kernel<<<1024, 256, 0, stream>>>((const float4*)Y, mink, maxk);
    ssim_kernel<<<2048, 256, 0, stream>>>(X, Y, u7, mink, maxk, sum);
    finalize_kernel<<<1, 1, 0, stream>>>(sum, (float*)d_out);
}